// Round 6
// baseline (231.592 us; speedup 1.0000x reference)
//
#include <hip/hip_runtime.h>
#include <math.h>

#define HX 48
#define WX 48
#define OMC 216
#define HY 96
#define WY 96

// ws layout (floats):
//  om  @ 0          : 1,990,656
//  wt2 @ 1,990,656  :   147,456
//  wt1 @ 2,138,112  :    36,864
//  yt  @ 2,174,976  : 2,359,296
//  shr @ 4,534,272  : 7,962,624   (pc [3*576*4096] first, then rs reuses it)
//  pt  @ 12,496,896 : 7,077,888   (3456 blocks * 2048)

// ---------- prep: wt2[k][ic][oc256]; wt1[k][c][oc64] ----------
__global__ __launch_bounds__(256) void prep_w_kernel(
    const float* __restrict__ w_om, const float* __restrict__ w_dc,
    float* __restrict__ wt2, float* __restrict__ wt1) {
  int idx = blockIdx.x * 256 + threadIdx.x;
  if (idx < 9 * 64 * 256) {
    int oc = idx & 255, ic = (idx >> 8) & 63, k = idx >> 14;
    wt2[idx] = (oc < OMC) ? w_om[oc * 576 + ic * 9 + k] : 0.0f;
  } else {
    int j = idx - 9 * 64 * 256;  // < 36864
    int oc = j & 63, c = (j >> 6) & 63, k = j >> 12;
    wt1[j] = w_dc[oc * 576 + c * 9 + k];
  }
}

// ---------- y[b][c][p] -> yt[b][p][c] ----------
__global__ __launch_bounds__(256) void ytr_kernel(const float* __restrict__ y,
                                                  float* __restrict__ yt) {
  __shared__ float tile[64][65];
  int blk = blockIdx.x;  // 576 = 4b * 144
  int b = blk / 144;
  int p0 = (blk % 144) * 64;
  int t = threadIdx.x;
  int pl = t & 63;
  int cb = t >> 6;
#pragma unroll
  for (int i = 0; i < 16; ++i) {
    int c = cb * 16 + i;
    tile[c][pl] = y[((size_t)(b * 64 + c)) * 9216 + p0 + pl];
  }
  __syncthreads();
  int cw = t & 63;
  int pb = t >> 6;
#pragma unroll
  for (int i = 0; i < 16; ++i) {
    int p = pb * 16 + i;
    yt[((size_t)(b * 9216 + p0 + p)) * 64 + cw] = tile[cw][p];
  }
}

// ---------- conv K-part: stage 3 taps up front, then 192-iter GEMM ----------
__global__ __launch_bounds__(256, 6) void conv_part_kernel(
    const float* __restrict__ x, const float* __restrict__ wt2,
    float* __restrict__ pc) {
  __shared__ float sval[3 * 1024];              // 12 KB
  int t = threadIdx.x;
  int bid = blockIdx.x;                         // 1728
  int logical = (bid & 7) * 216 + (bid >> 3);   // bijective XCD swizzle
  int p = logical / 576;
  int tile576 = logical % 576;
  int b = tile576 / 144;
  int tl = tile576 % 144;
  int h0 = (tl / 12) * 4;
  int w0 = (tl % 12) * 4;
  int k0 = p * 3;
  int s_ic = t >> 2;
  int s_row = t & 3;
  const float* xp = x + (size_t)b * 64 * 2304 + (size_t)s_ic * 2304;

  // stage all 3 taps (12 independent clamped loads in flight)
#pragma unroll
  for (int tap = 0; tap < 3; ++tap) {
    int k = k0 + tap;
    int dy = k / 3 - 1, dx = k % 3 - 1;
    int hh = h0 + s_row + dy;
    int ww = w0 + dx;
    bool hv = (unsigned)hh < (unsigned)HX;
    int hc = min(max(hh, 0), HX - 1);
    const float* xr = xp + hc * WX;
    int wc0 = min(max(ww + 0, 0), WX - 1);
    int wc1 = min(max(ww + 1, 0), WX - 1);
    int wc2 = min(max(ww + 2, 0), WX - 1);
    int wc3 = min(max(ww + 3, 0), WX - 1);
    float4 v;
    v.x = xr[wc0] * ((hv && (unsigned)(ww + 0) < (unsigned)WX) ? 1.f : 0.f);
    v.y = xr[wc1] * ((hv && (unsigned)(ww + 1) < (unsigned)WX) ? 1.f : 0.f);
    v.z = xr[wc2] * ((hv && (unsigned)(ww + 2) < (unsigned)WX) ? 1.f : 0.f);
    v.w = xr[wc3] * ((hv && (unsigned)(ww + 3) < (unsigned)WX) ? 1.f : 0.f);
    *(float4*)&sval[tap * 1024 + s_ic * 16 + s_row * 4] = v;
  }
  __syncthreads();

  int ocq = t & 63;
  int pxq = t >> 6;
  float acc[4][4];
#pragma unroll
  for (int i = 0; i < 4; ++i)
#pragma unroll
    for (int j = 0; j < 4; ++j) acc[i][j] = 0.0f;

#pragma unroll
  for (int tap = 0; tap < 3; ++tap) {
    const float* wk = wt2 + (size_t)(k0 + tap) * 16384;
    const float* svt = &sval[tap * 1024];
#pragma unroll 8
    for (int c = 0; c < 64; ++c) {
      float4 wv = *(const float4*)&wk[c * 256 + 4 * ocq];
      float4 vv = *(const float4*)&svt[c * 16 + 4 * pxq];
      acc[0][0] += wv.x * vv.x; acc[0][1] += wv.x * vv.y;
      acc[0][2] += wv.x * vv.z; acc[0][3] += wv.x * vv.w;
      acc[1][0] += wv.y * vv.x; acc[1][1] += wv.y * vv.y;
      acc[1][2] += wv.y * vv.z; acc[1][3] += wv.y * vv.w;
      acc[2][0] += wv.z * vv.x; acc[2][1] += wv.z * vv.y;
      acc[2][2] += wv.z * vv.z; acc[2][3] += wv.z * vv.w;
      acc[3][0] += wv.w * vv.x; acc[3][1] += wv.w * vv.y;
      acc[3][2] += wv.w * vv.z; acc[3][3] += wv.w * vv.w;
    }
  }

  float* pb = pc + (size_t)(p * 576 + tile576) * 4096;
#pragma unroll
  for (int i = 0; i < 4; ++i) {
    *(float4*)&pb[(4 * ocq + i) * 16 + 4 * pxq] =
        make_float4(acc[i][0], acc[i][1], acc[i][2], acc[i][3]);
  }
}

// ---------- creduce: sum 3 conv parts + bias -> om ----------
__global__ __launch_bounds__(256) void creduce_kernel(
    const float* __restrict__ pc, const float* __restrict__ bom,
    float* __restrict__ om) {
  int tile = blockIdx.x;  // 0..575
  int b = tile / 144;
  int tl = tile % 144;
  int h0 = (tl / 12) * 4;
  int w0 = (tl % 12) * 4;
  int n = threadIdx.x;            // oc = n
  if (n >= OMC) return;
  const float4* p0 = (const float4*)(pc + (size_t)(0 * 576 + tile) * 4096);
  const float4* p1 = (const float4*)(pc + (size_t)(1 * 576 + tile) * 4096);
  const float4* p2 = (const float4*)(pc + (size_t)(2 * 576 + tile) * 4096);
  float bv = bom[n];
#pragma unroll
  for (int q = 0; q < 4; ++q) {   // q = px row
    int j = n * 4 + q;
    float4 a = p0[j], c = p1[j], d = p2[j];
    float4 o;
    o.x = a.x + c.x + d.x + bv;
    o.y = a.y + c.y + d.y + bv;
    o.z = a.z + c.z + d.z + bv;
    o.w = a.w + c.w + d.w + bv;
    *(float4*)&om[((size_t)(b * OMC + n)) * 2304 + (h0 + q) * WX + w0] = o;
  }
}

// ---------- resize: LDS-staged, one block per (b,k,g) ----------
__global__ __launch_bounds__(256) void resize_kernel(const float* __restrict__ om,
                                                     float* __restrict__ rs) {
  __shared__ float sC[3][2304];
  int blk = blockIdx.x;         // 288 = b*72 + k*8 + g
  int g = blk % 8;
  int k = (blk / 8) % 9;
  int b = blk / 72;
  const float* omb = om + (size_t)b * OMC * 2304;
  const float* s0 = omb + (size_t)(g * 18 + k * 2) * 2304;
  const float* s1 = s0 + 2304;
  const float* s2 = omb + (size_t)(144 + g * 9 + k) * 2304;
  for (int i = threadIdx.x; i < 1728; i += 256) {
    int ch = i / 576, idx = i - ch * 576;
    const float4* src = (const float4*)(ch == 0 ? s0 : (ch == 1 ? s1 : s2));
    ((float4*)sC[ch])[idx] = src[idx];
  }
  __syncthreads();
  int dy = k / 3 - 1, dx = k % 3 - 1;
  float* o = rs + (size_t)(((b * 9 + k) * 8 + g) * 3) * 9216;
  for (int px = threadIdx.x; px < 9216; px += 256) {
    int h = px / 96, w = px - h * 96;
    float sh = fmaxf(h * 0.5f - 0.25f, 0.f);
    float sw = fmaxf(w * 0.5f - 0.25f, 0.f);
    int i0h = (int)sh; float th = sh - (float)i0h;
    int i0w = (int)sw; float tw = sw - (float)i0w;
    int i1h = min(i0h + 1, HX - 1);
    int i1w = min(i0w + 1, WX - 1);
    float r00 = (1.f - th) * (1.f - tw), r01 = (1.f - th) * tw;
    float r10 = th * (1.f - tw),         r11 = th * tw;
    int a00 = i0h * WX + i0w, a01 = i0h * WX + i1w;
    int a10 = i1h * WX + i0w, a11 = i1h * WX + i1w;
    float oy = r00 * sC[0][a00] + r01 * sC[0][a01] + r10 * sC[0][a10] + r11 * sC[0][a11];
    float ox = r00 * sC[1][a00] + r01 * sC[1][a01] + r10 * sC[1][a10] + r11 * sC[1][a11];
    float mv = r00 * sC[2][a00] + r01 * sC[2][a01] + r10 * sC[2][a10] + r11 * sC[2][a11];
    float mm = 1.f / (1.f + __expf(-mv));
    o[px]         = (float)(h + dy) + oy;
    o[9216 + px]  = (float)(w + dx) + ox;
    o[18432 + px] = mm;
  }
}

// ---------- deform K-part: gather 3 taps up front, then 192-iter GEMM ----------
// NOTE: 3rd macro param must NOT be named w/x/y/z/s/d — member-access capture!
#define MAD4(d, s, mw)                                                  \
  d.x += (mw) * s.x; d.y += (mw) * s.y; d.z += (mw) * s.z; d.w += (mw) * s.w;

__global__ __launch_bounds__(256, 6) void deform_part_kernel(
    const float* __restrict__ yt, const float* __restrict__ rs,
    const float* __restrict__ wt1, float* __restrict__ pt) {
  __shared__ float sval[192 * 34];              // 26112 B -> 6 blocks/CU
  int t = threadIdx.x;
  int bid = blockIdx.x;                         // 3456
  int logical = (bid & 7) * 432 + (bid >> 3);   // bijective XCD swizzle
  int part = logical / 1152;                    // 0..2
  int t32 = logical % 1152;
  int b = t32 / 288;
  int tl = t32 % 288;
  int h0 = (tl / 24) * 8;
  int w0 = (tl % 24) * 4;
  int k0 = part * 3;

  // gather role: one (group, px) per thread, 3 taps
  int gpx = t & 31;
  int g = t >> 5;                // 0..7
  int gh = h0 + (gpx >> 2);
  int gw = w0 + (gpx & 3);
  int px96 = gh * WY + gw;
  const float* rsb = rs + (size_t)b * 1990656 + px96;   // 9*8*3*9216
  const float* ytb = yt + (size_t)b * 9216 * 64;
  int gc = g * 8;

#pragma unroll
  for (int tap = 0; tap < 3; ++tap) {
    const float* r0 = rsb + (size_t)(((k0 + tap) * 8 + g) * 3) * 9216;
    float py = r0[0], pxf = r0[9216], m = r0[18432];
    float y0f = floorf(py), x0f = floorf(pxf);
    float ty = py - y0f, tx = pxf - x0f;
    int y0 = (int)y0f, x0 = (int)x0f;
    int y1 = y0 + 1, x1 = x0 + 1;
    float w00 = (1.f - ty) * (1.f - tx) * m, w01 = (1.f - ty) * tx * m;
    float w10 = ty * (1.f - tx) * m,         w11 = ty * tx * m;
    w00 = ((unsigned)y0 < HY && (unsigned)x0 < WY) ? w00 : 0.f;
    w01 = ((unsigned)y0 < HY && (unsigned)x1 < WY) ? w01 : 0.f;
    w10 = ((unsigned)y1 < HY && (unsigned)x0 < WY) ? w10 : 0.f;
    w11 = ((unsigned)y1 < HY && (unsigned)x1 < WY) ? w11 : 0.f;
    int y0c = min(max(y0, 0), HY - 1), y1c = min(max(y1, 0), HY - 1);
    int x0c = min(max(x0, 0), WY - 1), x1c = min(max(x1, 0), WY - 1);
    const float* p00 = ytb + (size_t)(y0c * WY + x0c) * 64 + gc;
    const float* p01 = ytb + (size_t)(y0c * WY + x1c) * 64 + gc;
    const float* p10 = ytb + (size_t)(y1c * WY + x0c) * 64 + gc;
    const float* p11 = ytb + (size_t)(y1c * WY + x1c) * 64 + gc;
    float4 s0 = {0, 0, 0, 0}, s1 = {0, 0, 0, 0};
    float4 cA, cB;
    cA = *(const float4*)p00; cB = *(const float4*)(p00 + 4);
    MAD4(s0, cA, w00) MAD4(s1, cB, w00)
    cA = *(const float4*)p01; cB = *(const float4*)(p01 + 4);
    MAD4(s0, cA, w01) MAD4(s1, cB, w01)
    cA = *(const float4*)p10; cB = *(const float4*)(p10 + 4);
    MAD4(s0, cA, w10) MAD4(s1, cB, w10)
    cA = *(const float4*)p11; cB = *(const float4*)(p11 + 4);
    MAD4(s0, cA, w11) MAD4(s1, cB, w11)
    float* dst = &sval[(tap * 64 + gc) * 34 + gpx];
    dst[0 * 34] = s0.x; dst[1 * 34] = s0.y; dst[2 * 34] = s0.z; dst[3 * 34] = s0.w;
    dst[4 * 34] = s1.x; dst[5 * 34] = s1.y; dst[6 * 34] = s1.z; dst[7 * 34] = s1.w;
  }
  __syncthreads();

  // GEMM: 4oc x 2px per thread, 192 K-iters uninterrupted
  int ocq = t & 15;
  int pxq = t >> 4;              // 0..15 -> px {2*pxq, 2*pxq+1}
  float acc[4][2];
#pragma unroll
  for (int i = 0; i < 4; ++i) { acc[i][0] = 0.f; acc[i][1] = 0.f; }

#pragma unroll
  for (int tap = 0; tap < 3; ++tap) {
    const float* wk = wt1 + (size_t)(k0 + tap) * 4096;
    const float* svt = &sval[tap * 64 * 34];
#pragma unroll 8
    for (int c = 0; c < 64; ++c) {
      float4 wv = *(const float4*)&wk[c * 64 + 4 * ocq];
      float2 vv = *(const float2*)&svt[c * 34 + 2 * pxq];
      acc[0][0] += wv.x * vv.x; acc[0][1] += wv.x * vv.y;
      acc[1][0] += wv.y * vv.x; acc[1][1] += wv.y * vv.y;
      acc[2][0] += wv.z * vv.x; acc[2][1] += wv.z * vv.y;
      acc[3][0] += wv.w * vv.x; acc[3][1] += wv.w * vv.y;
    }
  }

  // partials: pt[logical*2048 + oc*32 + px]
  float* pb = pt + (size_t)logical * 2048;
#pragma unroll
  for (int i = 0; i < 4; ++i) {
    *(float2*)&pb[(4 * ocq + i) * 32 + 2 * pxq] = make_float2(acc[i][0], acc[i][1]);
  }
}

// ---------- dreduce: sum 3 deform parts + bias + relu -> out ----------
__global__ __launch_bounds__(256) void dreduce_kernel(
    const float* __restrict__ pt, const float* __restrict__ bdc,
    float* __restrict__ out) {
  int tile = blockIdx.x;  // 0..1151
  int b = tile / 288;
  int tl = tile % 288;
  int h0 = (tl / 24) * 8;
  int w0 = (tl % 24) * 4;
  int n = threadIdx.x;
  int oc = n >> 2;
  int q = n & 3;
  const float4* p0 = (const float4*)(pt + (size_t)(0 * 1152 + tile) * 2048);
  const float4* p1 = (const float4*)(pt + (size_t)(1 * 1152 + tile) * 2048);
  const float4* p2 = (const float4*)(pt + (size_t)(2 * 1152 + tile) * 2048);
  float bv = bdc[oc];
#pragma unroll
  for (int r = 0; r < 2; ++r) {
    int j4 = oc * 8 + q * 2 + r;       // float4 index into 2048-float tile
    int ph = q * 2 + r;
    float4 a = p0[j4], c = p1[j4], d = p2[j4];
    float4 o;
    o.x = fmaxf(a.x + c.x + d.x + bv, 0.f);
    o.y = fmaxf(a.y + c.y + d.y + bv, 0.f);
    o.z = fmaxf(a.z + c.z + d.z + bv, 0.f);
    o.w = fmaxf(a.w + c.w + d.w + bv, 0.f);
    *(float4*)&out[((size_t)(b * 64 + oc) * 96 + (h0 + ph)) * 96 + w0] = o;
  }
}

extern "C" void kernel_launch(void* const* d_in, const int* in_sizes, int n_in,
                              void* d_out, int out_size, void* d_ws, size_t ws_size,
                              hipStream_t stream) {
  const float* x = (const float*)d_in[0];
  const float* y = (const float*)d_in[1];
  const float* w_om = (const float*)d_in[2];
  const float* b_om = (const float*)d_in[3];
  const float* w_dc = (const float*)d_in[4];
  const float* b_dc = (const float*)d_in[5];
  float* out = (float*)d_out;

  float* om  = (float*)d_ws;           // 1,990,656 f
  float* wt2 = om + 1990656;           //   147,456 f
  float* wt1 = wt2 + 147456;           //    36,864 f
  float* yt  = wt1 + 36864;            // 2,359,296 f
  float* shr = yt + 2359296;           // 7,962,624 f (pc then rs)
  float* pc  = shr;                    // 7,077,888 f (dead before rs written)
  float* rs  = shr;                    // 7,962,624 f
  float* pt  = shr + 7962624;          // 7,077,888 f

  prep_w_kernel<<<720, 256, 0, stream>>>(w_om, w_dc, wt2, wt1);
  ytr_kernel<<<576, 256, 0, stream>>>(y, yt);
  conv_part_kernel<<<1728, 256, 0, stream>>>(x, wt2, pc);
  creduce_kernel<<<576, 256, 0, stream>>>(pc, b_om, om);
  resize_kernel<<<288, 256, 0, stream>>>(om, rs);
  deform_part_kernel<<<3456, 256, 0, stream>>>(yt, rs, wt1, pt);
  dreduce_kernel<<<1152, 256, 0, stream>>>(pt, b_dc, out);
}

// Round 7
// 118.720 us; speedup vs baseline: 1.9507x; 1.9507x over previous
//
#include <hip/hip_runtime.h>
#include <math.h>

#define HX 48
#define WX 48
#define OMC 216
#define HY 96
#define WY 96

typedef __attribute__((ext_vector_type(8))) short bf16x8;
typedef __attribute__((ext_vector_type(4))) float f32x4;

__device__ inline unsigned short f2bf(float f) {
  unsigned u = __float_as_uint(f);
  return (unsigned short)((u + 0x7fffu + ((u >> 16) & 1u)) >> 16);  // RNE
}
__device__ inline unsigned pk2(float a, float b) {
  return (unsigned)f2bf(a) | ((unsigned)f2bf(b) << 16);
}

// ws layout (floats):
//  om  @ 0          : 1,990,656
//  ap2 @ 1,990,656  :    73,728   (147,456 bf16: conv A-frags [3p][6s][16m][64l][8])
//  ap1 @ 2,064,384  :    18,432   ( 36,864 bf16: deform A-frags [3p][6s][4w][64l][8])
//  yt  @ 2,082,816  : 2,359,296
//  shr @ 4,442,112  : 7,962,624   (pc [3*576*4096] first, then rs reuses it)
//  pt  @ 12,404,736 : 7,077,888
//  total 19,482,624 f ~= 77.9 MiB

// ---------- prep: pack bf16 MFMA A-fragments for both GEMMs ----------
__global__ __launch_bounds__(256) void prep_pack_kernel(
    const float* __restrict__ w_om, const float* __restrict__ w_dc,
    unsigned short* __restrict__ ap2, unsigned short* __restrict__ ap1) {
  int idx = blockIdx.x * 256 + threadIdx.x;   // 0..184319
  if (idx < 147456) {
    int j = idx & 7;
    int tmp = idx >> 3;
    int l = tmp & 63; tmp >>= 6;
    int m = tmp & 15; tmp >>= 4;              // 0..17
    int s = tmp % 6, p = tmp / 6;
    int oc = m * 16 + (l & 15);
    int kk = s * 32 + (l >> 4) * 8 + j;       // 0..191
    int tap = kk >> 6, c = kk & 63;
    int k = p * 3 + tap;
    ap2[idx] = (oc < OMC) ? f2bf(w_om[oc * 576 + c * 9 + k]) : (unsigned short)0;
  } else {
    int i2 = idx - 147456;                    // < 36864
    int j = i2 & 7;
    int tmp = i2 >> 3;
    int l = tmp & 63; tmp >>= 6;
    int w = tmp & 3; tmp >>= 2;               // 0..17
    int s = tmp % 6, p = tmp / 6;
    int oc = w * 16 + (l & 15);
    int kk = s * 32 + (l >> 4) * 8 + j;
    int tap = kk >> 6, c = kk & 63;
    ap1[i2] = f2bf(w_dc[oc * 576 + c * 9 + p * 3 + tap]);
  }
}

// ---------- y[b][c][p] -> yt[b][p][c] (fp32) ----------
__global__ __launch_bounds__(256) void ytr_kernel(const float* __restrict__ y,
                                                  float* __restrict__ yt) {
  __shared__ float tile[64][65];
  int blk = blockIdx.x;  // 576 = 4b * 144
  int b = blk / 144;
  int p0 = (blk % 144) * 64;
  int t = threadIdx.x;
  int pl = t & 63;
  int cb = t >> 6;
#pragma unroll
  for (int i = 0; i < 16; ++i) {
    int c = cb * 16 + i;
    tile[c][pl] = y[((size_t)(b * 64 + c)) * 9216 + p0 + pl];
  }
  __syncthreads();
  int cw = t & 63;
  int pb = t >> 6;
#pragma unroll
  for (int i = 0; i < 16; ++i) {
    int p = pb * 16 + i;
    yt[((size_t)(b * 9216 + p0 + p)) * 64 + cw] = tile[cw][p];
  }
}

// ---------- conv K-part via MFMA: 256oc x 16px, taps 3p..3p+2 ----------
__global__ __launch_bounds__(256) void conv_mfma_kernel(
    const float* __restrict__ x, const unsigned short* __restrict__ ap2,
    float* __restrict__ pc) {
  __shared__ unsigned short sB[3][16][72];    // 6912 B, [tap][px][c]
  int t = threadIdx.x;
  int bid = blockIdx.x;                       // 1728
  int logical = (bid & 7) * 216 + (bid >> 3); // bijective XCD swizzle
  int p = logical / 576;
  int tile576 = logical % 576;
  int b = tile576 / 144;
  int tl = tile576 % 144;
  int h0 = (tl / 12) * 4;
  int w0 = (tl % 12) * 4;
  int k0 = p * 3;
  int s_ic = t >> 2;
  int s_row = t & 3;
  const float* xp = x + (size_t)b * 64 * 2304 + (size_t)s_ic * 2304;

#pragma unroll
  for (int tap = 0; tap < 3; ++tap) {
    int k = k0 + tap;
    int dy = k / 3 - 1, dx = k % 3 - 1;
    int hh = h0 + s_row + dy;
    int ww = w0 + dx;
    bool hv = (unsigned)hh < (unsigned)HX;
    int hc = min(max(hh, 0), HX - 1);
    const float* xr = xp + hc * WX;
#pragma unroll
    for (int j = 0; j < 4; ++j) {
      int wcj = min(max(ww + j, 0), WX - 1);
      float v = xr[wcj] * ((hv && (unsigned)(ww + j) < (unsigned)WX) ? 1.f : 0.f);
      sB[tap][s_row * 4 + j][s_ic] = f2bf(v);
    }
  }
  __syncthreads();

  int w = t >> 6;
  int l = t & 63;
  int lr = l & 15;
  int lg = l >> 4;
  f32x4 acc[4] = {};
#pragma unroll
  for (int s = 0; s < 6; ++s) {
    int tap = s >> 1;
    int c0 = (s & 1) * 32;
    bf16x8 bv = *(const bf16x8*)&sB[tap][lr][c0 + lg * 8];
#pragma unroll
    for (int m = 0; m < 4; ++m) {
      bf16x8 av = *(const bf16x8*)(ap2 +
          (size_t)((((p * 6 + s) * 16) + w * 4 + m) * 64 + l) * 8);
      acc[m] = __builtin_amdgcn_mfma_f32_16x16x32_bf16(av, bv, acc[m], 0, 0, 0);
    }
  }
  float* pb = pc + (size_t)(p * 576 + tile576) * 4096;
#pragma unroll
  for (int m = 0; m < 4; ++m) {
#pragma unroll
    for (int i = 0; i < 4; ++i) {
      int oc = (w * 4 + m) * 16 + lg * 4 + i;
      pb[oc * 16 + lr] = acc[m][i];
    }
  }
}

// ---------- creduce: sum 3 conv parts + bias -> om (fp32) ----------
__global__ __launch_bounds__(256) void creduce_kernel(
    const float* __restrict__ pc, const float* __restrict__ bom,
    float* __restrict__ om) {
  int tile = blockIdx.x;  // 0..575
  int b = tile / 144;
  int tl = tile % 144;
  int h0 = (tl / 12) * 4;
  int w0 = (tl % 12) * 4;
  int n = threadIdx.x;    // oc
  if (n >= OMC) return;
  const float4* p0 = (const float4*)(pc + (size_t)(0 * 576 + tile) * 4096);
  const float4* p1 = (const float4*)(pc + (size_t)(1 * 576 + tile) * 4096);
  const float4* p2 = (const float4*)(pc + (size_t)(2 * 576 + tile) * 4096);
  float bv = bom[n];
#pragma unroll
  for (int q = 0; q < 4; ++q) {   // px row
    int j = n * 4 + q;
    float4 a = p0[j], c = p1[j], d = p2[j];
    float4 o;
    o.x = a.x + c.x + d.x + bv;
    o.y = a.y + c.y + d.y + bv;
    o.z = a.z + c.z + d.z + bv;
    o.w = a.w + c.w + d.w + bv;
    *(float4*)&om[((size_t)(b * OMC + n)) * 2304 + (h0 + q) * WX + w0] = o;
  }
}

// ---------- resize: LDS-staged, one block per (b,k,g) ----------
__global__ __launch_bounds__(256) void resize_kernel(const float* __restrict__ om,
                                                     float* __restrict__ rs) {
  __shared__ float sC[3][2304];
  int blk = blockIdx.x;         // 288 = b*72 + k*8 + g
  int g = blk % 8;
  int k = (blk / 8) % 9;
  int b = blk / 72;
  const float* omb = om + (size_t)b * OMC * 2304;
  const float* s0 = omb + (size_t)(g * 18 + k * 2) * 2304;
  const float* s1 = s0 + 2304;
  const float* s2 = omb + (size_t)(144 + g * 9 + k) * 2304;
  for (int i = threadIdx.x; i < 1728; i += 256) {
    int ch = i / 576, idx = i - ch * 576;
    const float4* src = (const float4*)(ch == 0 ? s0 : (ch == 1 ? s1 : s2));
    ((float4*)sC[ch])[idx] = src[idx];
  }
  __syncthreads();
  int dy = k / 3 - 1, dx = k % 3 - 1;
  float* o = rs + (size_t)(((b * 9 + k) * 8 + g) * 3) * 9216;
  for (int px = threadIdx.x; px < 9216; px += 256) {
    int h = px / 96, w = px - h * 96;
    float sh = fmaxf(h * 0.5f - 0.25f, 0.f);
    float sw = fmaxf(w * 0.5f - 0.25f, 0.f);
    int i0h = (int)sh; float th = sh - (float)i0h;
    int i0w = (int)sw; float tw = sw - (float)i0w;
    int i1h = min(i0h + 1, HX - 1);
    int i1w = min(i0w + 1, WX - 1);
    float r00 = (1.f - th) * (1.f - tw), r01 = (1.f - th) * tw;
    float r10 = th * (1.f - tw),         r11 = th * tw;
    int a00 = i0h * WX + i0w, a01 = i0h * WX + i1w;
    int a10 = i1h * WX + i0w, a11 = i1h * WX + i1w;
    float oy = r00 * sC[0][a00] + r01 * sC[0][a01] + r10 * sC[0][a10] + r11 * sC[0][a11];
    float ox = r00 * sC[1][a00] + r01 * sC[1][a01] + r10 * sC[1][a10] + r11 * sC[1][a11];
    float mv = r00 * sC[2][a00] + r01 * sC[2][a01] + r10 * sC[2][a10] + r11 * sC[2][a11];
    float mm = 1.f / (1.f + __expf(-mv));
    o[px]         = (float)(h + dy) + oy;
    o[9216 + px]  = (float)(w + dx) + ox;
    o[18432 + px] = mm;
  }
}

// ---------- deform K-part via MFMA: 64oc x 64px, taps 3p..3p+2 ----------
// NOTE: 3rd macro param must NOT be named w/x/y/z/s/d — member-access capture!
#define MAD4(d, s, mw)                                                  \
  d.x += (mw) * s.x; d.y += (mw) * s.y; d.z += (mw) * s.z; d.w += (mw) * s.w;

__global__ __launch_bounds__(256) void deform_mfma_kernel(
    const float* __restrict__ yt, const float* __restrict__ rs,
    const unsigned short* __restrict__ ap1, float* __restrict__ pt) {
  __shared__ unsigned short svalT[3][64][72];   // 27648 B, [tap][px][c]
  int t = threadIdx.x;
  int bid = blockIdx.x;                         // 1728
  int logical = (bid & 7) * 216 + (bid >> 3);   // bijective XCD swizzle
  int p = logical / 576;
  int tile576 = logical % 576;
  int b = tile576 / 144;
  int tl = tile576 % 144;
  int h0 = (tl / 12) * 8;
  int w0 = (tl % 12) * 8;
  int k0 = p * 3;

  int pl = t & 63;               // px within 8x8 tile
  int g0 = t >> 6;               // gathers groups g0 and g0+4
  int gh = h0 + (pl >> 3);
  int gw = w0 + (pl & 7);
  int px96 = gh * WY + gw;
  const float* rsb = rs + (size_t)b * 1990656 + px96;
  const float* ytb = yt + (size_t)b * 9216 * 64;

#pragma unroll
  for (int tap = 0; tap < 3; ++tap) {
#pragma unroll
    for (int gg = 0; gg < 2; ++gg) {
      int g = g0 + gg * 4;
      int gc = g * 8;
      const float* r0 = rsb + (size_t)(((k0 + tap) * 8 + g) * 3) * 9216;
      float py = r0[0], pxf = r0[9216], m = r0[18432];
      float y0f = floorf(py), x0f = floorf(pxf);
      float ty = py - y0f, tx = pxf - x0f;
      int y0 = (int)y0f, x0 = (int)x0f;
      int y1 = y0 + 1, x1 = x0 + 1;
      float w00 = (1.f - ty) * (1.f - tx) * m, w01 = (1.f - ty) * tx * m;
      float w10 = ty * (1.f - tx) * m,         w11 = ty * tx * m;
      w00 = ((unsigned)y0 < HY && (unsigned)x0 < WY) ? w00 : 0.f;
      w01 = ((unsigned)y0 < HY && (unsigned)x1 < WY) ? w01 : 0.f;
      w10 = ((unsigned)y1 < HY && (unsigned)x0 < WY) ? w10 : 0.f;
      w11 = ((unsigned)y1 < HY && (unsigned)x1 < WY) ? w11 : 0.f;
      int y0c = min(max(y0, 0), HY - 1), y1c = min(max(y1, 0), HY - 1);
      int x0c = min(max(x0, 0), WY - 1), x1c = min(max(x1, 0), WY - 1);
      const float* p00 = ytb + (size_t)(y0c * WY + x0c) * 64 + gc;
      const float* p01 = ytb + (size_t)(y0c * WY + x1c) * 64 + gc;
      const float* p10 = ytb + (size_t)(y1c * WY + x0c) * 64 + gc;
      const float* p11 = ytb + (size_t)(y1c * WY + x1c) * 64 + gc;
      float4 s0 = {0, 0, 0, 0}, s1 = {0, 0, 0, 0};
      float4 cA, cB;
      cA = *(const float4*)p00; cB = *(const float4*)(p00 + 4);
      MAD4(s0, cA, w00) MAD4(s1, cB, w00)
      cA = *(const float4*)p01; cB = *(const float4*)(p01 + 4);
      MAD4(s0, cA, w01) MAD4(s1, cB, w01)
      cA = *(const float4*)p10; cB = *(const float4*)(p10 + 4);
      MAD4(s0, cA, w10) MAD4(s1, cB, w10)
      cA = *(const float4*)p11; cB = *(const float4*)(p11 + 4);
      MAD4(s0, cA, w11) MAD4(s1, cB, w11)
      *(uint4*)&svalT[tap][pl][gc] =
          make_uint4(pk2(s0.x, s0.y), pk2(s0.z, s0.w), pk2(s1.x, s1.y), pk2(s1.z, s1.w));
    }
  }
  __syncthreads();

  // MFMA: wave w -> oc[16w..16w+16), 4 px-fragments, K = 192
  int w = t >> 6;
  int l = t & 63;
  int lr = l & 15;
  int lg = l >> 4;
  f32x4 acc[4] = {};
#pragma unroll
  for (int s = 0; s < 6; ++s) {
    int tap = s >> 1;
    int c0 = (s & 1) * 32;
    bf16x8 av = *(const bf16x8*)(ap1 +
        (size_t)(((p * 6 + s) * 4 + w) * 64 + l) * 8);
#pragma unroll
    for (int f = 0; f < 4; ++f) {
      bf16x8 bv = *(const bf16x8*)&svalT[tap][f * 16 + lr][c0 + lg * 8];
      acc[f] = __builtin_amdgcn_mfma_f32_16x16x32_bf16(av, bv, acc[f], 0, 0, 0);
    }
  }
  float* pb = pt + (size_t)(p * 576 + tile576) * 4096;   // [oc64][px64]
#pragma unroll
  for (int f = 0; f < 4; ++f) {
#pragma unroll
    for (int i = 0; i < 4; ++i) {
      int oc = w * 16 + lg * 4 + i;
      pb[oc * 64 + f * 16 + lr] = acc[f][i];
    }
  }
}

// ---------- dreduce: sum 3 deform parts + bias + relu -> out ----------
__global__ __launch_bounds__(256) void dreduce_kernel(
    const float* __restrict__ pt, const float* __restrict__ bdc,
    float* __restrict__ out) {
  int tile = blockIdx.x;  // 0..575
  int b = tile / 144;
  int tl = tile % 144;
  int h0 = (tl / 12) * 8;
  int w0 = (tl % 12) * 8;
  int n = threadIdx.x;
  int oc = n >> 2;
  int rq = n & 3;
  const float4* p0 = (const float4*)(pt + (size_t)(0 * 576 + tile) * 4096);
  const float4* p1 = (const float4*)(pt + (size_t)(1 * 576 + tile) * 4096);
  const float4* p2 = (const float4*)(pt + (size_t)(2 * 576 + tile) * 4096);
  float bv = bdc[oc];
#pragma unroll
  for (int r = 0; r < 4; ++r) {
    int px4 = rq * 4 + r;           // 0..15 (float4 chunks of 64px)
    int j4 = oc * 16 + px4;
    int dh = px4 >> 1;
    int dw = (px4 & 1) * 4;
    float4 a = p0[j4], c = p1[j4], d = p2[j4];
    float4 o;
    o.x = fmaxf(a.x + c.x + d.x + bv, 0.f);
    o.y = fmaxf(a.y + c.y + d.y + bv, 0.f);
    o.z = fmaxf(a.z + c.z + d.z + bv, 0.f);
    o.w = fmaxf(a.w + c.w + d.w + bv, 0.f);
    *(float4*)&out[((size_t)(b * 64 + oc) * 96 + (h0 + dh)) * 96 + w0 + dw] = o;
  }
}

extern "C" void kernel_launch(void* const* d_in, const int* in_sizes, int n_in,
                              void* d_out, int out_size, void* d_ws, size_t ws_size,
                              hipStream_t stream) {
  const float* x = (const float*)d_in[0];
  const float* y = (const float*)d_in[1];
  const float* w_om = (const float*)d_in[2];
  const float* b_om = (const float*)d_in[3];
  const float* w_dc = (const float*)d_in[4];
  const float* b_dc = (const float*)d_in[5];
  float* out = (float*)d_out;

  float* om  = (float*)d_ws;                       // 1,990,656 f
  unsigned short* ap2 = (unsigned short*)(om + 1990656);   // 147,456 bf16
  unsigned short* ap1 = ap2 + 147456;              //  36,864 bf16
  float* yt  = (float*)(ap1 + 36864);              // 2,359,296 f
  float* shr = yt + 2359296;                       // 7,962,624 f (pc then rs)
  float* pc  = shr;                                // 7,077,888 f
  float* rs  = shr;                                // 7,962,624 f
  float* pt  = shr + 7962624;                      // 7,077,888 f

  prep_pack_kernel<<<720, 256, 0, stream>>>(w_om, w_dc, ap2, ap1);
  ytr_kernel<<<576, 256, 0, stream>>>(y, yt);
  conv_mfma_kernel<<<1728, 256, 0, stream>>>(x, ap2, pc);
  creduce_kernel<<<576, 256, 0, stream>>>(pc, b_om, om);
  resize_kernel<<<288, 256, 0, stream>>>(om, rs);
  deform_mfma_kernel<<<1728, 256, 0, stream>>>(yt, rs, ap1, pt);
  dreduce_kernel<<<576, 256, 0, stream>>>(pt, b_dc, out);
}